// Round 3
// baseline (1449.127 us; speedup 1.0000x reference)
//
#include <hip/hip_runtime.h>

// MSD: x[20000, 512, 3] fp32 -> msd[2000] fp32
// msd[td] = (1/(180*1536)) * sum_{i=0..179} sum_e (x[100i+td,e] - x[100i,e])^2
//
// Mapping: every reference pair (i, td) <-> (t = 100i + td, k = td/100),
// k in [0,20). Block <-> (128-frame range, element slice). Thread <-> frame t.
// For a block, needed origins i = t/100 - k span <= 21 rows -> staged in LDS
// once; inner reads are uniform-address ds_read_b128 broadcasts (low latency,
// conflict-free). Moving frame slice lives in registers (two 12-float4 halves).
// acc[20] per thread; flush = <=20 predicated atomics with scale folded in.

#define ROW4    384     // float4 per frame (1536 floats)
#define NORIG   180
#define TDMAX   2000
#define WIN     20
#define SLICES  16
#define S4      24      // float4 per slice (96 floats)
#define HALF    12      // float4 per half-slice
#define TBLK    156     // ceil(19900 valid frames / 128); max t = 19967 < 20000
#define SCALE   (1.0f / (1536.0f * 180.0f))

__global__ __launch_bounds__(128, 4)
void msd_kernel(const float4* __restrict__ x4, float* __restrict__ out) {
    __shared__ float4 sOrig[21 * S4];      // up to 21 origin rows, 8064 B

    const int bt  = blockIdx.x / SLICES;   // frame block
    const int s   = blockIdx.x % SLICES;   // element slice
    const int tid = threadIdx.x;
    const int t0  = bt * 128;
    const int t   = t0 + tid;
    const int c   = t / 100;

    const int cmin = t0 / 100;
    const int cmax = (t0 + 127) / 100;
    int iBase = cmin - (WIN - 1); if (iBase < 0) iBase = 0;
    int iTop  = cmax;             if (iTop > NORIG - 1) iTop = NORIG - 1;
    const int nRows = iTop - iBase + 1;    // 1..21
    const int sbase = s * S4;

    // stage origin rows (this slice) into LDS, coalesced
    for (int f = tid; f < nRows * S4; f += 128) {
        const int row = f / S4;
        const int q   = f - row * S4;
        sOrig[f] = x4[(size_t)((iBase + row) * 100) * ROW4 + sbase + q];
    }
    __syncthreads();

    const int rp = t - 100 * c;            // t % 100

    float acc[WIN];
    #pragma unroll
    for (int k = 0; k < WIN; ++k) acc[k] = 0.0f;

    const size_t mrow = (size_t)t * ROW4 + sbase;

    #pragma unroll
    for (int h = 0; h < 2; ++h) {
        float4 m[HALF];
        #pragma unroll
        for (int q = 0; q < HALF; ++q) m[q] = x4[mrow + h * HALF + q];

        #pragma unroll
        for (int k = 0; k < WIN; ++k) {
            const int i = c - k;
            const bool valid = (i >= 0) && (i <= NORIG - 1);
            const int row = valid ? (i - iBase) : 0;   // clamped: safe LDS read,
                                                       // garbage acc dropped at flush
            const float4* orow = &sOrig[row * S4 + h * HALF];

            float p = 0.0f;
            #pragma unroll
            for (int q = 0; q < HALF; ++q) {
                const float4 o = orow[q];
                float d;
                d = m[q].x - o.x; p += d * d;
                d = m[q].y - o.y; p += d * d;
                d = m[q].z - o.z; p += d * d;
                d = m[q].w - o.w; p += d * d;
            }
            acc[k] += p;
        }
    }

    // flush: td = 100k + rp, one predicated atomic per valid k
    #pragma unroll
    for (int k = 0; k < WIN; ++k) {
        const int i = c - k;
        if (i >= 0 && i <= NORIG - 1)
            atomicAdd(&out[100 * k + rp], acc[k] * SCALE);
    }
}

extern "C" void kernel_launch(void* const* d_in, const int* in_sizes, int n_in,
                              void* d_out, int out_size, void* d_ws, size_t ws_size,
                              hipStream_t stream) {
    const float4* x4 = (const float4*)d_in[0];
    float* out = (float*)d_out;

    hipMemsetAsync(out, 0, TDMAX * sizeof(float), stream);
    msd_kernel<<<TBLK * SLICES, 128, 0, stream>>>(x4, out);
}

// Round 4
// 268.296 us; speedup vs baseline: 5.4012x; 5.4012x over previous
//
#include <hip/hip_runtime.h>

// MSD: x[20000, 512, 3] fp32 -> msd[2000] fp32
// msd[td] = (1/(180*1536)) * sum_{i=0..179} sum_e (x[100i+td,e] - x[100i,e])^2
//
// Mapping: pair (i, td) <-> (t = 100i + td, k = td/100), k in [0,20).
// Block <-> (128 consecutive frames, element slice of 96 floats).
// Origins i = t/100 - k span <= 21 rows per block -> staged in LDS once;
// inner origin reads are uniform-address ds_read_b128 broadcasts (no
// conflicts, low latency). Moving data processed in SMALL tiles of 4 float4
// (16 VGPRs) with the kt loop forced non-unrolled -- R3's 12-float4 tile +
// unroll caused a scratch-spill catastrophe (2.3 GB scratch traffic).
// acc[20] per thread; flush = <=20 predicated atomics, scale folded in.

#define ROW4    384     // float4 per frame (1536 floats)
#define NORIG   180
#define TDMAX   2000
#define WIN     20
#define SLICES  16
#define S4      24      // float4 per slice (96 floats)
#define KT      6       // tiles of 4 float4 per slice
#define TBLK    156     // ceil(19900 valid frames / 128); max t = 19967 < 20000
#define SCALE   (1.0f / (1536.0f * 180.0f))

__global__ __launch_bounds__(128)
void msd_kernel(const float4* __restrict__ x4, float* __restrict__ out) {
    __shared__ float4 sOrig[21 * S4];      // up to 21 origin rows, 8064 B

    const int bt  = blockIdx.x / SLICES;   // frame block
    const int s   = blockIdx.x % SLICES;   // element slice
    const int tid = threadIdx.x;
    const int t0  = bt * 128;
    const int t   = t0 + tid;
    const int c   = t / 100;

    const int cmin = t0 / 100;
    const int cmax = (t0 + 127) / 100;
    int iBase = cmin - (WIN - 1); if (iBase < 0) iBase = 0;
    int iTop  = cmax;             if (iTop > NORIG - 1) iTop = NORIG - 1;
    const int nRows = iTop - iBase + 1;    // 1..21
    const int sbase = s * S4;

    // stage origin rows (this slice) into LDS, coalesced
    for (int f = tid; f < nRows * S4; f += 128) {
        const int row = f / S4;
        const int q   = f - row * S4;
        sOrig[f] = x4[(size_t)((iBase + row) * 100) * ROW4 + sbase + q];
    }
    __syncthreads();

    const int rp = t - 100 * c;            // t % 100

    float acc[WIN];
    #pragma unroll
    for (int k = 0; k < WIN; ++k) acc[k] = 0.0f;

    const size_t mrow = (size_t)t * ROW4 + sbase;

    #pragma unroll 1                       // keep ONE 4-float4 m-tile live
    for (int kt = 0; kt < KT; ++kt) {
        const size_t mb = mrow + kt * 4;
        const float4 m0 = x4[mb + 0];
        const float4 m1 = x4[mb + 1];
        const float4 m2 = x4[mb + 2];
        const float4 m3 = x4[mb + 3];
        const int obase = kt * 4;

        #pragma unroll
        for (int k = 0; k < WIN; ++k) {
            int row = c - k - iBase;
            row = (row < 0) ? 0 : ((row >= nRows) ? 0 : row);  // safe read;
                                                 // garbage acc dropped at flush
            const float4* orow = &sOrig[row * S4 + obase];
            const float4 o0 = orow[0];
            const float4 o1 = orow[1];
            const float4 o2 = orow[2];
            const float4 o3 = orow[3];

            float d, p;
            d = m0.x - o0.x; p  = d * d;
            d = m0.y - o0.y; p += d * d;
            d = m0.z - o0.z; p += d * d;
            d = m0.w - o0.w; p += d * d;
            d = m1.x - o1.x; p += d * d;
            d = m1.y - o1.y; p += d * d;
            d = m1.z - o1.z; p += d * d;
            d = m1.w - o1.w; p += d * d;
            d = m2.x - o2.x; p += d * d;
            d = m2.y - o2.y; p += d * d;
            d = m2.z - o2.z; p += d * d;
            d = m2.w - o2.w; p += d * d;
            d = m3.x - o3.x; p += d * d;
            d = m3.y - o3.y; p += d * d;
            d = m3.z - o3.z; p += d * d;
            d = m3.w - o3.w; p += d * d;
            acc[k] += p;
        }
    }

    // flush: td = 100k + rp, one predicated atomic per valid k
    #pragma unroll
    for (int k = 0; k < WIN; ++k) {
        const int i = c - k;
        if (i >= 0 && i <= NORIG - 1)
            atomicAdd(&out[100 * k + rp], acc[k] * SCALE);
    }
}

extern "C" void kernel_launch(void* const* d_in, const int* in_sizes, int n_in,
                              void* d_out, int out_size, void* d_ws, size_t ws_size,
                              hipStream_t stream) {
    const float4* x4 = (const float4*)d_in[0];
    float* out = (float*)d_out;

    hipMemsetAsync(out, 0, TDMAX * sizeof(float), stream);
    msd_kernel<<<TBLK * SLICES, 128, 0, stream>>>(x4, out);
}